// Round 1
// baseline (678.837 us; speedup 1.0000x reference)
//
#include <hip/hip_runtime.h>

// VolumeNormalizer: out[b] = v[b] / (sum_t |det(tet)| / 6)^(1/3)
// B=64, N_VERTS=100000 (300000 floats/row), N_TETS=200000 (3 int indices each).

constexpr int NV   = 100000;
constexpr int NT   = 200000;
constexpr int NB   = 64;
constexpr int ROW  = 3 * NV;     // 300000 floats per batch row
constexpr int ROW4 = ROW / 4;    // 75000 float4 per batch row (exact)

__global__ __launch_bounds__(64) void init_ws_kernel(float* __restrict__ ws) {
    ws[threadIdx.x] = 0.0f;      // ws is re-poisoned to 0xAA before every call
}

__global__ __launch_bounds__(256) void vol_reduce_kernel(
    const float* __restrict__ x,
    const int*   __restrict__ M,
    float*       __restrict__ ws)
{
    const int b = blockIdx.y;
    const float* __restrict__ v = x + (size_t)b * ROW;

    float acc = 0.0f;
    const int stride = gridDim.x * blockDim.x;
    for (int t = blockIdx.x * blockDim.x + threadIdx.x; t < NT; t += stride) {
        const int i0 = M[3 * t + 0];
        const int i1 = M[3 * t + 1];
        const int i2 = M[3 * t + 2];
        const float a00 = v[3 * i0 + 0], a01 = v[3 * i0 + 1], a02 = v[3 * i0 + 2];
        const float a10 = v[3 * i1 + 0], a11 = v[3 * i1 + 1], a12 = v[3 * i1 + 2];
        const float a20 = v[3 * i2 + 0], a21 = v[3 * i2 + 1], a22 = v[3 * i2 + 2];
        const float det = a00 * (a11 * a22 - a12 * a21)
                        - a01 * (a10 * a22 - a12 * a20)
                        + a02 * (a10 * a21 - a11 * a20);
        acc += fabsf(det);
    }

    // wave-64 shuffle reduction
    #pragma unroll
    for (int off = 32; off > 0; off >>= 1)
        acc += __shfl_down(acc, off, 64);

    __shared__ float sacc[4];
    const int lane = threadIdx.x & 63;
    const int wv   = threadIdx.x >> 6;
    if (lane == 0) sacc[wv] = acc;
    __syncthreads();
    if (threadIdx.x == 0)
        atomicAdd(&ws[b], sacc[0] + sacc[1] + sacc[2] + sacc[3]);
}

__global__ __launch_bounds__(64) void finalize_kernel(
    const float* __restrict__ ws, float* __restrict__ inv)
{
    const float S = ws[threadIdx.x];           // S = 6 * vol
    inv[threadIdx.x] = cbrtf(6.0f / S);        // 1 / (S/6)^(1/3)
}

__global__ __launch_bounds__(256) void scale_kernel(
    const float4* __restrict__ x,
    const float*  __restrict__ inv,
    float4*       __restrict__ out)
{
    const int idx = blockIdx.x * 256 + threadIdx.x;
    const int b   = idx / ROW4;                // magic-mul divide, cheap
    const float s = inv[b];
    float4 vv = x[idx];
    vv.x *= s; vv.y *= s; vv.z *= s; vv.w *= s;
    out[idx] = vv;
}

extern "C" void kernel_launch(void* const* d_in, const int* in_sizes, int n_in,
                              void* d_out, int out_size, void* d_ws, size_t ws_size,
                              hipStream_t stream)
{
    const float* x  = (const float*)d_in[0];   // (64, 300000) f32
    const int*   M  = (const int*)d_in[1];     // (200000, 3) int (harness converts ints to int32)
    float*       out = (float*)d_out;          // (64, 300000) f32
    float*       ws  = (float*)d_ws;           // ws[0..63]=sums, ws[64..127]=inv scales

    init_ws_kernel<<<1, 64, 0, stream>>>(ws);

    dim3 rgrid(64, NB);                        // 4096 blocks; ~12 tets/thread
    vol_reduce_kernel<<<rgrid, 256, 0, stream>>>(x, M, ws);

    finalize_kernel<<<1, 64, 0, stream>>>(ws, ws + 64);

    const int n4 = NB * ROW4;                  // 4,800,000 float4s; /256 = 18750 exact
    scale_kernel<<<n4 / 256, 256, 0, stream>>>((const float4*)x, ws + 64, (float4*)out);
}

// Round 2
// 238.591 us; speedup vs baseline: 2.8452x; 2.8452x over previous
//
#include <hip/hip_runtime.h>

// VolumeNormalizer: out[b] = v[b] / (sum_t |det(tet)| / 6)^(1/3)
// B=64, N_VERTS=100000 (300000 floats/row), N_TETS=200000.
//
// R2 structure: transpose x -> xt[c][b] (vertex-major) so the reduce pass can
// use lane=batch with fully-coalesced 256B gathers (R1 showed 2.1 GB of L2-miss
// traffic from uncoalesced per-batch gathers).

constexpr int NV   = 100000;
constexpr int NT   = 200000;
constexpr int NB   = 64;
constexpr int ROW  = 3 * NV;     // 300000 floats (coords) per batch row
constexpr int ROW4 = ROW / 4;    // 75000 float4 per batch row (exact)

__global__ __launch_bounds__(64) void init_ws_kernel(float* __restrict__ ws) {
    ws[threadIdx.x] = 0.0f;
}

// xt[c*64 + b] = x[b*ROW + c], tile 64 coords x 64 batches via LDS
__global__ __launch_bounds__(256) void transpose_kernel(
    const float* __restrict__ x, float* __restrict__ xt)
{
    __shared__ float tile[64][NB + 1];          // +1 pad: conflict-free both phases
    const int c0 = blockIdx.x * 64;
    const int lo = threadIdx.x & 63;
    const int hi = threadIdx.x >> 6;            // 0..3

    // read: consecutive lanes -> consecutive c (coalesced)
    #pragma unroll
    for (int k = 0; k < 16; ++k) {
        const int b = hi + 4 * k;
        const int c = c0 + lo;
        if (c < ROW) tile[lo][b] = x[(size_t)b * ROW + c];
    }
    __syncthreads();
    // write: consecutive lanes -> consecutive b (coalesced)
    #pragma unroll
    for (int k = 0; k < 16; ++k) {
        const int c = hi + 4 * k;
        if (c0 + c < ROW) xt[(size_t)(c0 + c) * NB + lo] = tile[c][lo];
    }
}

// One wave processes a contiguous chunk of tets; lane = batch.
// Per tet: 3 broadcast index loads + 9 coalesced 256B vertex loads.
__global__ __launch_bounds__(256) void vol_reduce_kernel(
    const float* __restrict__ xt,
    const int*   __restrict__ M,
    float*       __restrict__ ws)
{
    const int lane = threadIdx.x & 63;
    const int wib  = threadIdx.x >> 6;                       // wave in block (0..3)
    const int wid  = blockIdx.x * 4 + wib;                   // global wave id
    const int nw   = gridDim.x * 4;
    const int chunk = (NT + nw - 1) / nw;
    const int t0 = wid * chunk;
    const int t1 = min(NT, t0 + chunk);

    float acc = 0.0f;
    #pragma unroll 2
    for (int t = t0; t < t1; ++t) {
        const int i0 = M[3 * t + 0];
        const int i1 = M[3 * t + 1];
        const int i2 = M[3 * t + 2];
        const float* p0 = xt + (size_t)i0 * 192 + lane;      // (3*i0)*64
        const float* p1 = xt + (size_t)i1 * 192 + lane;
        const float* p2 = xt + (size_t)i2 * 192 + lane;
        const float a00 = p0[0], a01 = p0[64], a02 = p0[128];
        const float a10 = p1[0], a11 = p1[64], a12 = p1[128];
        const float a20 = p2[0], a21 = p2[64], a22 = p2[128];
        const float det = a00 * (a11 * a22 - a12 * a21)
                        - a01 * (a10 * a22 - a12 * a20)
                        + a02 * (a10 * a21 - a11 * a20);
        acc += fabsf(det);
    }

    // block pre-reduction: 4 waves each hold per-batch partials in lane b
    __shared__ float sacc[4][NB];
    sacc[wib][lane] = acc;
    __syncthreads();
    if (threadIdx.x < NB)
        atomicAdd(&ws[threadIdx.x],
                  sacc[0][threadIdx.x] + sacc[1][threadIdx.x] +
                  sacc[2][threadIdx.x] + sacc[3][threadIdx.x]);
}

// out = x * cbrt(6/S_b); the per-block redundant cbrt replaces a finalize launch
__global__ __launch_bounds__(256) void scale_kernel(
    const float4* __restrict__ x,
    const float*  __restrict__ ws,
    float4*       __restrict__ out)
{
    const int idx = blockIdx.x * 256 + threadIdx.x;
    const int b   = idx / ROW4;
    const float s = cbrtf(6.0f / ws[b]);
    float4 vv = x[idx];
    vv.x *= s; vv.y *= s; vv.z *= s; vv.w *= s;
    out[idx] = vv;
}

extern "C" void kernel_launch(void* const* d_in, const int* in_sizes, int n_in,
                              void* d_out, int out_size, void* d_ws, size_t ws_size,
                              hipStream_t stream)
{
    const float* x   = (const float*)d_in[0];  // (64, 300000) f32
    const int*   M   = (const int*)d_in[1];    // (200000, 3) int32
    float*       out = (float*)d_out;
    float*       ws  = (float*)d_ws;           // ws[0..63] = per-batch sums
    float*       xt  = ws + 256;               // 76.8 MB transposed verts (ws is scratch)

    init_ws_kernel<<<1, 64, 0, stream>>>(ws);

    transpose_kernel<<<(ROW + 63) / 64, 256, 0, stream>>>(x, xt);

    vol_reduce_kernel<<<1024, 256, 0, stream>>>(xt, M, ws);   // 4096 waves, ~49 tets each

    scale_kernel<<<NB * ROW4 / 256, 256, 0, stream>>>((const float4*)x, ws, (float4*)out);
}

// Round 4
// 220.137 us; speedup vs baseline: 3.0837x; 1.0838x over previous
//
#include <hip/hip_runtime.h>
#include <hip/hip_fp16.h>

// VolumeNormalizer: out[b] = v[b] / (sum_t |det(tet)| / 6)^(1/3)
// B=64, N_VERTS=100000 (ROW=300000 floats/row), N_TETS=200000.
//
// R3b: xt stored as fp16 (halves the 460 MB cache-gather traffic that bounds
// the reduce), ws-init fused into transpose, nontemporal output stores
// (via native ext_vector float4 — HIP_vector_type float4 is rejected by
// __builtin_nontemporal_store).

constexpr int NV   = 100000;
constexpr int NT   = 200000;
constexpr int NB   = 64;
constexpr int ROW  = 3 * NV;     // 300000 coords per batch row
constexpr int ROW4 = ROW / 4;    // 75000 float4 per row (exact)

typedef float vfloat4 __attribute__((ext_vector_type(4)));

// x (f32, batch-major) -> xt (f16, coord-major: xt[c*64 + b]); zeroes ws too.
__global__ __launch_bounds__(256) void transpose_kernel(
    const float* __restrict__ x, __half* __restrict__ xt, float* __restrict__ ws)
{
    __shared__ float tile[64][65];               // +1 pad
    if (blockIdx.x == 0 && threadIdx.x < NB) ws[threadIdx.x] = 0.0f;

    const int c0 = blockIdx.x * 64;
    const int l  = threadIdx.x & 63;
    const int w  = threadIdx.x >> 6;             // wave id 0..3

    const int c = c0 + l;
    if (c < ROW) {
        #pragma unroll
        for (int k = 0; k < 16; ++k) {           // wave w: batches w*16..w*16+15
            const int b = w * 16 + k;
            tile[l][b] = x[(size_t)b * ROW + c]; // 256B coalesced per wave
        }
    }
    __syncthreads();

    // write half2: lanes 0..31 of each half-wave cover all 64 batches
    const int b2 = (l & 31) * 2;
    #pragma unroll
    for (int k = 0; k < 8; ++k) {
        const int r  = (l >> 5) + 2 * w + 8 * k; // row within tile
        const int cc = c0 + r;
        if (cc < ROW) {
            __half2 h = __floats2half2_rn(tile[r][b2], tile[r][b2 + 1]);
            *(__half2*)&xt[(size_t)cc * NB + b2] = h;  // 128B coalesced
        }
    }
}

// lane = batch; per tet: 3 scalar index loads (wave-uniform) + 9 coalesced
// 128B fp16 gathers. fp32 math.
__global__ __launch_bounds__(256) void vol_reduce_kernel(
    const __half* __restrict__ xt,
    const int*    __restrict__ M,
    float*        __restrict__ ws)
{
    const int lane  = threadIdx.x & 63;
    const int wib   = threadIdx.x >> 6;
    const int wid   = blockIdx.x * 4 + wib;
    const int nw    = gridDim.x * 4;
    const int chunk = (NT + nw - 1) / nw;
    const int t0 = wid * chunk;
    const int t1 = min(NT, t0 + chunk);

    const __half* __restrict__ base = xt + lane;
    float acc = 0.0f;
    #pragma unroll 4
    for (int t = t0; t < t1; ++t) {
        const int i0 = M[3 * t + 0];
        const int i1 = M[3 * t + 1];
        const int i2 = M[3 * t + 2];
        const __half* p0 = base + (size_t)i0 * 192;   // (3*i)*64 halves
        const __half* p1 = base + (size_t)i1 * 192;
        const __half* p2 = base + (size_t)i2 * 192;
        const float a00 = __half2float(p0[0]);
        const float a01 = __half2float(p0[64]);
        const float a02 = __half2float(p0[128]);
        const float a10 = __half2float(p1[0]);
        const float a11 = __half2float(p1[64]);
        const float a12 = __half2float(p1[128]);
        const float a20 = __half2float(p2[0]);
        const float a21 = __half2float(p2[64]);
        const float a22 = __half2float(p2[128]);
        const float det = a00 * (a11 * a22 - a12 * a21)
                        - a01 * (a10 * a22 - a12 * a20)
                        + a02 * (a10 * a21 - a11 * a20);
        acc += fabsf(det);
    }

    __shared__ float sacc[4][NB];
    sacc[wib][lane] = acc;
    __syncthreads();
    if (threadIdx.x < NB)
        atomicAdd(&ws[threadIdx.x],
                  sacc[0][threadIdx.x] + sacc[1][threadIdx.x] +
                  sacc[2][threadIdx.x] + sacc[3][threadIdx.x]);
}

__global__ __launch_bounds__(256) void scale_kernel(
    const vfloat4* __restrict__ x,
    const float*   __restrict__ ws,
    vfloat4*       __restrict__ out)
{
    const int idx = blockIdx.x * 256 + threadIdx.x;
    const int b   = idx / ROW4;
    const float s = cbrtf(6.0f / ws[b]);
    vfloat4 vv = x[idx];
    vv *= s;
    __builtin_nontemporal_store(vv, &out[idx]);   // don't evict x/xt from L3
}

extern "C" void kernel_launch(void* const* d_in, const int* in_sizes, int n_in,
                              void* d_out, int out_size, void* d_ws, size_t ws_size,
                              hipStream_t stream)
{
    const float* x   = (const float*)d_in[0];  // (64, 300000) f32
    const int*   M   = (const int*)d_in[1];    // (200000, 3) int32
    float*       out = (float*)d_out;
    float*       ws  = (float*)d_ws;           // ws[0..63] = per-batch sums
    __half*      xt  = (__half*)(ws + 256);    // 38.4 MB fp16 transposed verts

    transpose_kernel<<<(ROW + 63) / 64, 256, 0, stream>>>(x, xt, ws);

    vol_reduce_kernel<<<2048, 256, 0, stream>>>(xt, M, ws);  // 8192 waves, 25 tets each

    scale_kernel<<<NB * ROW4 / 256, 256, 0, stream>>>((const vfloat4*)x, ws, (vfloat4*)out);
}